// Round 3
// baseline (295.094 us; speedup 1.0000x reference)
//
#include <hip/hip_runtime.h>
#include <hip/hip_bf16.h>

typedef __bf16 bf16_t;
typedef __bf16 bf16x8 __attribute__((ext_vector_type(8)));
typedef float  f32x4  __attribute__((ext_vector_type(4)));

__device__ __forceinline__ bf16x8 pack8(f32x4 a, f32x4 b) {
    bf16x8 h = { (bf16_t)a.x, (bf16_t)a.y, (bf16_t)a.z, (bf16_t)a.w,
                 (bf16_t)b.x, (bf16_t)b.y, (bf16_t)b.z, (bf16_t)b.w };
    return h;
}

// ---------------------------------------------------------------------------
// proj_norm: fused P = A @ W^T + bias, L2-row-normalize, store bf16.
// grid 512: blocks [0,256) -> X (K=1024), [256,512) -> Y (K=768).
// BM=32 rows, BN=256 (FULL width -> row norm computable in-block).
// 4 waves; wave w owns cols [w*64, w*64+64). MFMA operands loaded DIRECTLY
// from global fp32 (frag = 8 consecutive k = 32B contiguous), packed to bf16
// in-reg. No LDS in main loop; LDS only for the 4-wave ssq reduction.
// ---------------------------------------------------------------------------
__global__ __launch_bounds__(256) void proj_norm(
    const float* __restrict__ X, const float* __restrict__ Y,
    const float* __restrict__ Wxp, const float* __restrict__ bxp,
    const float* __restrict__ Wyp, const float* __restrict__ byp,
    bf16_t* __restrict__ Xn, bf16_t* __restrict__ Yn,
    float* __restrict__ sums)
{
    __shared__ float ssq[4][32];

    // zero rowsum/colsum (16384 floats) using the first 64 blocks
    if (blockIdx.x < 64) sums[blockIdx.x * 256 + threadIdx.x] = 0.0f;

    const int tid  = threadIdx.x;
    const int lane = tid & 63;
    const int wave = tid >> 6;
    const int quad = lane >> 4;
    const int c16  = lane & 15;

    const bool isY = blockIdx.x >= 256;
    const float* A    = isY ? Y   : X;
    const float* W    = isY ? Wyp : Wxp;
    const float* bias = isY ? byp : bxp;
    bf16_t* dst       = isY ? Yn  : Xn;
    const int K       = isY ? 768 : 1024;
    const int rowBase = (blockIdx.x & 255) * 32;

    // lane-fixed row pointers (k advances)
    const float* pa[2];
    const float* pb[4];
    #pragma unroll
    for (int mf = 0; mf < 2; ++mf)
        pa[mf] = &A[(size_t)(rowBase + mf * 16 + c16) * K + quad * 8];
    #pragma unroll
    for (int nf = 0; nf < 4; ++nf)
        pb[nf] = &W[(size_t)(wave * 64 + nf * 16 + c16) * K + quad * 8];

    f32x4 acc[2][4] = {};

    #pragma unroll 2
    for (int k0 = 0; k0 < K; k0 += 32) {
        bf16x8 aF[2], bF[4];
        #pragma unroll
        for (int mf = 0; mf < 2; ++mf) {
            f32x4 lo = *reinterpret_cast<const f32x4*>(pa[mf] + k0);
            f32x4 hi = *reinterpret_cast<const f32x4*>(pa[mf] + k0 + 4);
            aF[mf] = pack8(lo, hi);
        }
        #pragma unroll
        for (int nf = 0; nf < 4; ++nf) {
            f32x4 lo = *reinterpret_cast<const f32x4*>(pb[nf] + k0);
            f32x4 hi = *reinterpret_cast<const f32x4*>(pb[nf] + k0 + 4);
            bF[nf] = pack8(lo, hi);
        }
        #pragma unroll
        for (int mf = 0; mf < 2; ++mf)
            #pragma unroll
            for (int nf = 0; nf < 4; ++nf)
                acc[mf][nf] = __builtin_amdgcn_mfma_f32_16x16x32_bf16(
                    aF[mf], bF[nf], acc[mf][nf], 0, 0, 0);
    }

    // bias (before normalization, as in reference)
    #pragma unroll
    for (int nf = 0; nf < 4; ++nf) {
        float bb = bias[wave * 64 + nf * 16 + c16];
        #pragma unroll
        for (int mf = 0; mf < 2; ++mf)
            #pragma unroll
            for (int r = 0; r < 4; ++r)
                acc[mf][nf][r] += bb;
    }

    // per-row sum of squares: this wave's 64-col partial, butterfly over c16
    float s[2][4];
    #pragma unroll
    for (int mf = 0; mf < 2; ++mf)
        #pragma unroll
        for (int r = 0; r < 4; ++r) {
            float v = 0.f;
            #pragma unroll
            for (int nf = 0; nf < 4; ++nf)
                v += acc[mf][nf][r] * acc[mf][nf][r];
            v += __shfl_xor(v, 1, 64);
            v += __shfl_xor(v, 2, 64);
            v += __shfl_xor(v, 4, 64);
            v += __shfl_xor(v, 8, 64);
            s[mf][r] = v;
        }

    if (c16 == 0) {
        #pragma unroll
        for (int mf = 0; mf < 2; ++mf)
            #pragma unroll
            for (int r = 0; r < 4; ++r)
                ssq[wave][mf * 16 + quad * 4 + r] = s[mf][r];
    }
    __syncthreads();

    // normalize + store bf16 (scalar stores; 16 consecutive cols/instr)
    #pragma unroll
    for (int mf = 0; mf < 2; ++mf)
        #pragma unroll
        for (int r = 0; r < 4; ++r) {
            int row = mf * 16 + quad * 4 + r;
            float t = ssq[0][row] + ssq[1][row] + ssq[2][row] + ssq[3][row];
            float inv = 1.0f / fmaxf(sqrtf(t), 1e-8f);
            #pragma unroll
            for (int nf = 0; nf < 4; ++nf) {
                int col = wave * 64 + nf * 16 + c16;
                dst[(size_t)(rowBase + row) * 256 + col] =
                    (bf16_t)(acc[mf][nf][r] * inv);
            }
        }
}

// ---------------------------------------------------------------------------
// sim_gemm: e = exp(Xn @ Yn^T); rowsum/colsum/diag. BM=BN=128, K=256.
// NO LDS in main loop: MFMA fragments are 16B-contiguous in row-major global
// memory (A-layout m=lane&15, k=quad*8+j), so each lane loads its fragment
// straight from L1/L2 (Xn/Yn are 4MB each). Software double-buffered, zero
// barriers in the K-loop. LDS (1KB) used only for the epilogue reduction.
// ---------------------------------------------------------------------------
__global__ __launch_bounds__(256) void sim_gemm(
    const bf16_t* __restrict__ Xn, const bf16_t* __restrict__ Yn,
    float* __restrict__ rowsum, float* __restrict__ colsum,
    float* __restrict__ pos)
{
    __shared__ float red[256];

    const int tid  = threadIdx.x;
    const int lane = tid & 63;
    const int wave = tid >> 6;
    const int quad = lane >> 4;
    const int c16  = lane & 15;
    const int wy   = wave >> 1;
    const int wx   = wave & 1;
    const int rowBase = blockIdx.x * 128;
    const int colBase = blockIdx.y * 128;

    const bf16_t* pa[4];
    const bf16_t* pb[4];
    #pragma unroll
    for (int mf = 0; mf < 4; ++mf)
        pa[mf] = &Xn[(size_t)(rowBase + wy * 64 + mf * 16 + c16) * 256 + quad * 8];
    #pragma unroll
    for (int nf = 0; nf < 4; ++nf)
        pb[nf] = &Yn[(size_t)(colBase + wx * 64 + nf * 16 + c16) * 256 + quad * 8];

    f32x4 acc[4][4] = {};

    auto loadf = [&](bf16x8* A, bf16x8* B, int k0) {
        #pragma unroll
        for (int i = 0; i < 4; ++i) {
            A[i] = *reinterpret_cast<const bf16x8*>(pa[i] + k0);
            B[i] = *reinterpret_cast<const bf16x8*>(pb[i] + k0);
        }
    };
    auto mm = [&](bf16x8* A, bf16x8* B) {
        #pragma unroll
        for (int mf = 0; mf < 4; ++mf)
            #pragma unroll
            for (int nf = 0; nf < 4; ++nf)
                acc[mf][nf] = __builtin_amdgcn_mfma_f32_16x16x32_bf16(
                    A[mf], B[nf], acc[mf][nf], 0, 0, 0);
    };

    bf16x8 A0[4], B0[4], A1[4], B1[4];
    loadf(A0, B0, 0);
    #pragma unroll
    for (int kk = 0; kk < 4; ++kk) {
        int k = 2 * kk;
        if (k + 1 < 8) loadf(A1, B1, (k + 1) * 32);
        mm(A0, B0);
        if (k + 2 < 8) loadf(A0, B0, (k + 2) * 32);
        mm(A1, B1);
    }

    // ---- epilogue ----
    #pragma unroll
    for (int mf = 0; mf < 4; ++mf)
        #pragma unroll
        for (int nf = 0; nf < 4; ++nf)
            #pragma unroll
            for (int r = 0; r < 4; ++r)
                acc[mf][nf][r] = __expf(acc[mf][nf][r]);   // TAU = 1

    if (rowBase == colBase) {
        #pragma unroll
        for (int mf = 0; mf < 4; ++mf)
            #pragma unroll
            for (int nf = 0; nf < 4; ++nf)
                #pragma unroll
                for (int r = 0; r < 4; ++r) {
                    int lrow = wy * 64 + mf * 16 + quad * 4 + r;
                    int lcol = wx * 64 + nf * 16 + c16;
                    if (lrow == lcol) pos[rowBase + lrow] = acc[mf][nf][r];
                }
    }

    float rs[4][4];
    #pragma unroll
    for (int mf = 0; mf < 4; ++mf)
        #pragma unroll
        for (int r = 0; r < 4; ++r) {
            float v = acc[mf][0][r] + acc[mf][1][r] + acc[mf][2][r] + acc[mf][3][r];
            v += __shfl_xor(v, 1, 64);
            v += __shfl_xor(v, 2, 64);
            v += __shfl_xor(v, 4, 64);
            v += __shfl_xor(v, 8, 64);
            rs[mf][r] = v;
        }

    float cs[4];
    #pragma unroll
    for (int nf = 0; nf < 4; ++nf) {
        float v = 0.f;
        #pragma unroll
        for (int mf = 0; mf < 4; ++mf)
            #pragma unroll
            for (int r = 0; r < 4; ++r)
                v += acc[mf][nf][r];
        v += __shfl_xor(v, 16, 64);
        v += __shfl_xor(v, 32, 64);
        cs[nf] = v;
    }

    red[tid] = 0.f;
    __syncthreads();

    if (c16 == 0) {
        #pragma unroll
        for (int mf = 0; mf < 4; ++mf)
            #pragma unroll
            for (int r = 0; r < 4; ++r)
                atomicAdd(&red[wy * 64 + mf * 16 + quad * 4 + r], rs[mf][r]);
    }
    if (quad == 0) {
        #pragma unroll
        for (int nf = 0; nf < 4; ++nf)
            atomicAdd(&red[128 + wx * 64 + nf * 16 + c16], cs[nf]);
    }
    __syncthreads();

    if (tid < 128) atomicAdd(&rowsum[rowBase + tid], red[tid]);
    else           atomicAdd(&colsum[colBase + tid - 128], red[tid]);
}

// ---------------------------------------------------------------------------
__global__ __launch_bounds__(256) void finalize(
    const float* __restrict__ rowsum, const float* __restrict__ colsum,
    const float* __restrict__ pos, float* __restrict__ out)
{
    int i = blockIdx.x * 256 + threadIdx.x;
    float p = pos[i];
    out[i] = logf(colsum[i] - p) + logf(rowsum[i] - p) - 2.0f * logf(p);
}

// ---------------------------------------------------------------------------
extern "C" void kernel_launch(void* const* d_in, const int* in_sizes, int n_in,
                              void* d_out, int out_size, void* d_ws, size_t ws_size,
                              hipStream_t stream) {
    const float* X  = (const float*)d_in[0];
    const float* Y  = (const float*)d_in[1];
    const float* Wx = (const float*)d_in[2];
    const float* bx = (const float*)d_in[3];
    const float* Wy = (const float*)d_in[4];
    const float* by = (const float*)d_in[5];
    float* out = (float*)d_out;

    char* ws = (char*)d_ws;
    bf16_t* Xn = (bf16_t*)(ws);                    // 4 MB: 8192x256 bf16
    bf16_t* Yn = (bf16_t*)(ws + (4u << 20));       // 4 MB
    float*  rowsum = (float*)(ws + (8u << 20));    // 32 KB
    float*  colsum = rowsum + 8192;
    float*  pos    = colsum + 8192;

    proj_norm<<<512, 256, 0, stream>>>(X, Y, Wx, bx, Wy, by, Xn, Yn, rowsum);
    sim_gemm<<<dim3(64, 64), 256, 0, stream>>>(Xn, Yn, rowsum, colsum, pos);
    finalize<<<32, 256, 0, stream>>>(rowsum, colsum, pos, out);
}

// Round 4
// 195.952 us; speedup vs baseline: 1.5060x; 1.5060x over previous
//
#include <hip/hip_runtime.h>
#include <hip/hip_bf16.h>

typedef __bf16 bf16_t;
typedef __bf16 bf16x4 __attribute__((ext_vector_type(4)));
typedef __bf16 bf16x8 __attribute__((ext_vector_type(8)));
typedef float  f32x4  __attribute__((ext_vector_type(4)));

// 16B async global->LDS DMA. LDS dest is wave-uniform base + lane*16.
__device__ __forceinline__ void gl_lds16(const void* g, void* l) {
    __builtin_amdgcn_global_load_lds(
        (const __attribute__((address_space(1))) unsigned int*)g,
        (__attribute__((address_space(3))) unsigned int*)l, 16, 0, 0);
}

// ---- fp8 e4m3 (OCP) packing: 4 floats -> 4 bytes ----
#if __has_builtin(__builtin_amdgcn_cvt_pk_fp8_f32)
__device__ __forceinline__ unsigned int pack4_e4m3(float a, float b, float c, float d) {
    int w = 0;
    w = __builtin_amdgcn_cvt_pk_fp8_f32(a, b, w, false);  // bytes 0,1
    w = __builtin_amdgcn_cvt_pk_fp8_f32(c, d, w, true);   // bytes 2,3
    return (unsigned int)w;
}
#else
__device__ __forceinline__ unsigned char cvt1_e4m3(float x) {
    unsigned u = __float_as_uint(x);
    unsigned sign = (u >> 24) & 0x80u;
    float a = fabsf(x);
    if (a < 7.8125e-3f) {                 // below 2^-7: subnormal, quantum 2^-9
        int q = (int)(a * 512.0f + 0.5f);
        return (unsigned char)(sign | q);
    }
    if (a >= 448.0f) return (unsigned char)(sign | 0x7E);
    unsigned au = u & 0x7FFFFFFFu;
    unsigned lsb = (au >> 20) & 1u;
    au += 0x7FFFFu + lsb;                 // RNE at mantissa bit 20
    int exp = (int)(au >> 23) - 127;
    unsigned man = (au >> 20) & 7u;
    return (unsigned char)(sign | ((unsigned)(exp + 7) << 3) | man);
}
__device__ __forceinline__ unsigned int pack4_e4m3(float a, float b, float c, float d) {
    return (unsigned int)cvt1_e4m3(a) | ((unsigned int)cvt1_e4m3(b) << 8) |
           ((unsigned int)cvt1_e4m3(c) << 16) | ((unsigned int)cvt1_e4m3(d) << 24);
}
#endif

// ---------------------------------------------------------------------------
// proj_gemm (fused X and Y): P[M,256] = A[M,K] @ W[256,K]^T + bias  (R2 struct)
// ---------------------------------------------------------------------------
__global__ __launch_bounds__(256) void proj_gemm(
    const float* __restrict__ X, const float* __restrict__ Y,
    const float* __restrict__ Wxp, const float* __restrict__ bxp,
    const float* __restrict__ Wyp, const float* __restrict__ byp,
    float* __restrict__ Xp, float* __restrict__ Yp)
{
    __shared__ bf16_t As[64][72];
    __shared__ bf16_t Bs[64][72];

    const int tid  = threadIdx.x;
    const int lane = tid & 63;
    const int wave = tid >> 6;
    const int quad = lane >> 4;
    const int c16  = lane & 15;
    const int wy   = wave >> 1;
    const int wx   = wave & 1;

    const bool isY = blockIdx.x >= 128;
    const float* A    = isY ? Y   : X;
    const float* W    = isY ? Wyp : Wxp;
    const float* bias = isY ? byp : bxp;
    float* P          = isY ? Yp  : Xp;
    const int K     = isY ? 768 : 1024;
    const int kit   = K >> 6;
    const int rowBase = (blockIdx.x & 127) * 64;
    const int colBase = blockIdx.y * 64;

    const int lr = tid >> 2;
    const int lc = tid & 3;

    f32x4 ra[4], rb[4];
    const float* pa = &A[(size_t)(rowBase + lr) * K + lc * 16];
    const float* pw = &W[(size_t)(colBase + lr) * K + lc * 16];

    #pragma unroll
    for (int j = 0; j < 4; ++j) { ra[j] = *reinterpret_cast<const f32x4*>(pa + j * 4);
                                  rb[j] = *reinterpret_cast<const f32x4*>(pw + j * 4); }

    f32x4 acc[2][2] = {};

    for (int k = 0; k < kit; ++k) {
        __syncthreads();
        #pragma unroll
        for (int u = 0; u < 2; ++u) {
            f32x4 a0 = ra[2*u], a1 = ra[2*u+1], b0 = rb[2*u], b1 = rb[2*u+1];
            bf16x8 ha = { (bf16_t)a0.x,(bf16_t)a0.y,(bf16_t)a0.z,(bf16_t)a0.w,
                          (bf16_t)a1.x,(bf16_t)a1.y,(bf16_t)a1.z,(bf16_t)a1.w };
            bf16x8 hb = { (bf16_t)b0.x,(bf16_t)b0.y,(bf16_t)b0.z,(bf16_t)b0.w,
                          (bf16_t)b1.x,(bf16_t)b1.y,(bf16_t)b1.z,(bf16_t)b1.w };
            *reinterpret_cast<bf16x8*>(&As[lr][lc * 16 + u * 8]) = ha;
            *reinterpret_cast<bf16x8*>(&Bs[lr][lc * 16 + u * 8]) = hb;
        }
        if (k + 1 < kit) {
            const float* qa = pa + (k + 1) * 64;
            const float* qw = pw + (k + 1) * 64;
            #pragma unroll
            for (int j = 0; j < 4; ++j) { ra[j] = *reinterpret_cast<const f32x4*>(qa + j * 4);
                                          rb[j] = *reinterpret_cast<const f32x4*>(qw + j * 4); }
        }
        __syncthreads();

        #pragma unroll
        for (int s = 0; s < 2; ++s) {
            bf16x8 aF[2], bF[2];
            #pragma unroll
            for (int mf = 0; mf < 2; ++mf)
                aF[mf] = *reinterpret_cast<const bf16x8*>(&As[wy*32 + mf*16 + c16][s*32 + quad*8]);
            #pragma unroll
            for (int nf = 0; nf < 2; ++nf)
                bF[nf] = *reinterpret_cast<const bf16x8*>(&Bs[wx*32 + nf*16 + c16][s*32 + quad*8]);
            #pragma unroll
            for (int mf = 0; mf < 2; ++mf)
                #pragma unroll
                for (int nf = 0; nf < 2; ++nf)
                    acc[mf][nf] = __builtin_amdgcn_mfma_f32_16x16x32_bf16(
                        aF[mf], bF[nf], acc[mf][nf], 0, 0, 0);
        }
    }

    #pragma unroll
    for (int nf = 0; nf < 2; ++nf) {
        int gcol = colBase + wx * 32 + nf * 16 + c16;
        float b = bias[gcol];
        #pragma unroll
        for (int mf = 0; mf < 2; ++mf)
            #pragma unroll
            for (int r = 0; r < 4; ++r) {
                int grow = rowBase + wy * 32 + mf * 16 + quad * 4 + r;
                P[(size_t)grow * 256 + gcol] = acc[mf][nf][r] + b;
            }
    }
}

// ---------------------------------------------------------------------------
// rownorm: L2-normalize rows of Xp/Yp -> fp8 e4m3 (plain row-major).
// Also zeroes rowsum/colsum. One wave per row; uint (4 fp8) store per lane.
// ---------------------------------------------------------------------------
__global__ __launch_bounds__(256) void rownorm(
    const float* __restrict__ Xp, const float* __restrict__ Yp,
    unsigned int* __restrict__ Xn8, unsigned int* __restrict__ Yn8,
    float* __restrict__ sums)
{
    if (blockIdx.x < 64) sums[blockIdx.x * 256 + threadIdx.x] = 0.0f;

    const int wave = threadIdx.x >> 6;
    const int lane = threadIdx.x & 63;
    const int r = blockIdx.x * 4 + wave;

    const float* src;
    unsigned int* dst;
    int row;
    if (r < 8192) { src = Xp; dst = Xn8; row = r; }
    else          { src = Yp; dst = Yn8; row = r - 8192; }

    f32x4 v = *reinterpret_cast<const f32x4*>(&src[(size_t)row * 256 + lane * 4]);
    float s = v.x * v.x + v.y * v.y + v.z * v.z + v.w * v.w;
    #pragma unroll
    for (int o = 32; o >= 1; o >>= 1) s += __shfl_xor(s, o, 64);
    float inv = 1.0f / fmaxf(sqrtf(s), 1e-8f);

    dst[(size_t)row * 64 + lane] =
        pack4_e4m3(v.x * inv, v.y * inv, v.z * inv, v.w * inv);
}

// ---------------------------------------------------------------------------
// sim_gemm (fp8): e = exp(Xn @ Yn^T); rowsum/colsum/diag.
// BM=BN=128, BK=64, 4 slabs. Double-buffered LDS via 16B DMA.
// Chunk-XOR swizzle (c ^ (row>>1)&3) applied to the GLOBAL source chunk per
// lane: DMA lanes stay contiguous in LDS, global stays row-major (same 64B
// line, permuted), and the ds_read_b64 fragment reads are exactly even across
// banks (4 words/bank = b64 minimum).
// ---------------------------------------------------------------------------
__global__ __launch_bounds__(256) void sim_gemm(
    const unsigned char* __restrict__ Xn8, const unsigned char* __restrict__ Yn8,
    float* __restrict__ rowsum, float* __restrict__ colsum,
    float* __restrict__ pos)
{
    __shared__ unsigned char As[2][128 * 64];
    __shared__ unsigned char Bs[2][128 * 64];
    __shared__ float red[256];

    const int tid  = threadIdx.x;
    const int lane = tid & 63;
    const int wave = tid >> 6;
    const int quad = lane >> 4;
    const int c16  = lane & 15;
    const int wy   = wave >> 1;
    const int wx   = wave & 1;
    const int rowBase = blockIdx.x * 128;
    const int colBase = blockIdx.y * 128;

    f32x4 acc[4][4] = {};

    // stage slab s (cols s*64..s*64+63) into buffer b: 4 DMA instrs/thread
    auto stage = [&](int s, int b) {
        #pragma unroll
        for (int t = 0; t < 2; ++t) {
            int r0 = wave * 32 + t * 16;              // wave-uniform LDS base row
            int r  = r0 + (lane >> 2);
            int gch = (lane & 3) ^ ((r >> 1) & 3);    // swizzled global chunk
            gl_lds16(&Xn8[(size_t)(rowBase + r) * 256 + s * 64 + gch * 16], &As[b][r0 * 64]);
            gl_lds16(&Yn8[(size_t)(colBase + r) * 256 + s * 64 + gch * 16], &Bs[b][r0 * 64]);
        }
    };

    stage(0, 0);

    for (int k = 0; k < 4; ++k) {
        const int cur = k & 1;
        __syncthreads();                 // drains cur's DMA; orders prev reads
        if (k < 3) stage(k + 1, cur ^ 1);

        #pragma unroll
        for (int s = 0; s < 2; ++s) {    // two K=32 sub-steps within the slab
            long aF[4], bF[4];
            #pragma unroll
            for (int mf = 0; mf < 4; ++mf) {
                int row = wy * 64 + mf * 16 + c16;
                int pch = ((s << 1) | (quad >> 1)) ^ ((row >> 1) & 3);
                aF[mf] = *reinterpret_cast<const long*>(
                    &As[cur][row * 64 + pch * 16 + (quad & 1) * 8]);
            }
            #pragma unroll
            for (int nf = 0; nf < 4; ++nf) {
                int row = wx * 64 + nf * 16 + c16;
                int pch = ((s << 1) | (quad >> 1)) ^ ((row >> 1) & 3);
                bF[nf] = *reinterpret_cast<const long*>(
                    &Bs[cur][row * 64 + pch * 16 + (quad & 1) * 8]);
            }
            #pragma unroll
            for (int mf = 0; mf < 4; ++mf)
                #pragma unroll
                for (int nf = 0; nf < 4; ++nf)
                    acc[mf][nf] = __builtin_amdgcn_mfma_f32_16x16x32_fp8_fp8(
                        aF[mf], bF[nf], acc[mf][nf], 0, 0, 0);
        }
    }

    // ---- epilogue ----
    #pragma unroll
    for (int mf = 0; mf < 4; ++mf)
        #pragma unroll
        for (int nf = 0; nf < 4; ++nf)
            #pragma unroll
            for (int r = 0; r < 4; ++r)
                acc[mf][nf][r] = __expf(acc[mf][nf][r]);   // TAU = 1

    if (rowBase == colBase) {
        #pragma unroll
        for (int mf = 0; mf < 4; ++mf)
            #pragma unroll
            for (int nf = 0; nf < 4; ++nf)
                #pragma unroll
                for (int r = 0; r < 4; ++r) {
                    int lrow = wy * 64 + mf * 16 + quad * 4 + r;
                    int lcol = wx * 64 + nf * 16 + c16;
                    if (lrow == lcol) pos[rowBase + lrow] = acc[mf][nf][r];
                }
    }

    float rs[4][4];
    #pragma unroll
    for (int mf = 0; mf < 4; ++mf)
        #pragma unroll
        for (int r = 0; r < 4; ++r) {
            float v = acc[mf][0][r] + acc[mf][1][r] + acc[mf][2][r] + acc[mf][3][r];
            v += __shfl_xor(v, 1, 64);
            v += __shfl_xor(v, 2, 64);
            v += __shfl_xor(v, 4, 64);
            v += __shfl_xor(v, 8, 64);
            rs[mf][r] = v;
        }

    float cs[4];
    #pragma unroll
    for (int nf = 0; nf < 4; ++nf) {
        float v = 0.f;
        #pragma unroll
        for (int mf = 0; mf < 4; ++mf)
            #pragma unroll
            for (int r = 0; r < 4; ++r)
                v += acc[mf][nf][r];
        v += __shfl_xor(v, 16, 64);
        v += __shfl_xor(v, 32, 64);
        cs[nf] = v;
    }

    red[tid] = 0.f;
    __syncthreads();

    if (c16 == 0) {
        #pragma unroll
        for (int mf = 0; mf < 4; ++mf)
            #pragma unroll
            for (int r = 0; r < 4; ++r)
                atomicAdd(&red[wy * 64 + mf * 16 + quad * 4 + r], rs[mf][r]);
    }
    if (quad == 0) {
        #pragma unroll
        for (int nf = 0; nf < 4; ++nf)
            atomicAdd(&red[128 + wx * 64 + nf * 16 + c16], cs[nf]);
    }
    __syncthreads();

    if (tid < 128) atomicAdd(&rowsum[rowBase + tid], red[tid]);
    else           atomicAdd(&colsum[colBase + tid - 128], red[tid]);
}

// ---------------------------------------------------------------------------
__global__ __launch_bounds__(256) void finalize(
    const float* __restrict__ rowsum, const float* __restrict__ colsum,
    const float* __restrict__ pos, float* __restrict__ out)
{
    int i = blockIdx.x * 256 + threadIdx.x;
    float p = pos[i];
    out[i] = logf(colsum[i] - p) + logf(rowsum[i] - p) - 2.0f * logf(p);
}

// ---------------------------------------------------------------------------
extern "C" void kernel_launch(void* const* d_in, const int* in_sizes, int n_in,
                              void* d_out, int out_size, void* d_ws, size_t ws_size,
                              hipStream_t stream) {
    const float* X  = (const float*)d_in[0];
    const float* Y  = (const float*)d_in[1];
    const float* Wx = (const float*)d_in[2];
    const float* bx = (const float*)d_in[3];
    const float* Wy = (const float*)d_in[4];
    const float* by = (const float*)d_in[5];
    float* out = (float*)d_out;

    char* ws = (char*)d_ws;
    float*        Xp  = (float*)(ws);                  // 8 MB
    float*        Yp  = (float*)(ws + (8u  << 20));    // 8 MB
    unsigned int* Xn8 = (unsigned int*)(ws + (16u << 20));  // 2 MB: 8192x256 fp8
    unsigned int* Yn8 = (unsigned int*)(ws + (18u << 20));  // 2 MB
    float*  rowsum = (float*)(ws + (20u << 20));
    float*  colsum = rowsum + 8192;
    float*  pos    = colsum + 8192;

    proj_gemm<<<dim3(256, 4), 256, 0, stream>>>(X, Y, Wx, bx, Wy, by, Xp, Yp);
    rownorm<<<4096, 256, 0, stream>>>(Xp, Yp, Xn8, Yn8, rowsum);
    sim_gemm<<<dim3(64, 64), 256, 0, stream>>>(
        (const unsigned char*)Xn8, (const unsigned char*)Yn8, rowsum, colsum, pos);
    finalize<<<32, 256, 0, stream>>>(rowsum, colsum, pos, out);
}

// Round 5
// 168.244 us; speedup vs baseline: 1.7540x; 1.1647x over previous
//
#include <hip/hip_runtime.h>
#include <hip/hip_bf16.h>

typedef __bf16 bf16_t;
typedef __bf16 bf16x4 __attribute__((ext_vector_type(4)));
typedef __bf16 bf16x8 __attribute__((ext_vector_type(8)));
typedef float  f32x4  __attribute__((ext_vector_type(4)));
typedef unsigned long u64;
typedef u64 u64x2 __attribute__((ext_vector_type(2)));

// ---- fp8 e4m3 (OCP) conversion ----
#if __has_builtin(__builtin_amdgcn_cvt_pk_fp8_f32)
__device__ __forceinline__ unsigned char cvt1_e4m3(float x) {
    return (unsigned char)(__builtin_amdgcn_cvt_pk_fp8_f32(x, x, 0, false) & 0xff);
}
#else
__device__ __forceinline__ unsigned char cvt1_e4m3(float x) {
    unsigned u = __float_as_uint(x);
    unsigned sign = (u >> 24) & 0x80u;
    float a = fabsf(x);
    if (a < 7.8125e-3f) { int q = (int)(a * 512.0f + 0.5f); return (unsigned char)(sign | q); }
    if (a >= 448.0f) return (unsigned char)(sign | 0x7E);
    unsigned au = u & 0x7FFFFFFFu;
    unsigned lsb = (au >> 20) & 1u;
    au += 0x7FFFFu + lsb;
    int exp = (int)(au >> 23) - 127;
    unsigned man = (au >> 20) & 7u;
    return (unsigned char)(sign | ((unsigned)(exp + 7) << 3) | man);
}
#endif

// Fragment-major byte offset within a 16-row tile (tile = row>>4, stride 4096):
// off(row,k) = ((k>>6)*4 + ((k>>3)&3))*256 + (row&15)*16 + ((k>>5)&1)*8 + (k&7)
// Wave fragment load for (16-row tile, 64-K slab): base + lane*16, fully
// contiguous 1024B; each lane's 16B = {substep0 j0..7, substep1 j0..7}.
__device__ __forceinline__ int frag_off(int lr, int k) {
    return ((lr >> 4) << 12) + ((((k >> 6) << 2) + ((k >> 3) & 3)) << 8)
         + ((lr & 15) << 4) + (((k >> 5) & 1) << 3) + (k & 7);
}

// ---------------------------------------------------------------------------
// proj_norm: fused P = A@W^T + bias -> L2 row-normalize -> fp8 e4m3 in
// FRAGMENT-MAJOR layout. BM=64 rows, BN=256 (full width -> norm in-block).
// 512 threads (8 waves, wave (wy=w>>2: 32-row half, wx=w&3: 64-col strip)).
// Single-buffer LDS (pad 40) + register prefetch, 2 barriers/iter.
// Also zeroes rowsum/colsum (first 32 blocks).
// ---------------------------------------------------------------------------
__global__ __launch_bounds__(512) void proj_norm(
    const float* __restrict__ X, const float* __restrict__ Y,
    const float* __restrict__ Wxp, const float* __restrict__ bxp,
    const float* __restrict__ Wyp, const float* __restrict__ byp,
    unsigned char* __restrict__ Xt, unsigned char* __restrict__ Yt,
    float* __restrict__ sums)
{
    __shared__ bf16_t Abuf[64][40];    // +8 pad: b128 frag reads conflict-free
    __shared__ bf16_t Wbuf[256][40];
    __shared__ float  ssqL[4][64];
    __shared__ unsigned char obuf[16384];

    if (blockIdx.x < 32) sums[blockIdx.x * 512 + threadIdx.x] = 0.0f;

    const int tid  = threadIdx.x;
    const int lane = tid & 63;
    const int wave = tid >> 6;     // 0..7
    const int quad = lane >> 4;
    const int c16  = lane & 15;
    const int wy   = wave >> 2;    // 0..1: rows wy*32
    const int wx   = wave & 3;     // 0..3: cols wx*64

    const bool isY = blockIdx.x >= 128;
    const float* A    = isY ? Y   : X;
    const float* W    = isY ? Wyp : Wxp;
    const float* bias = isY ? byp : bxp;
    unsigned char* dst = isY ? Yt : Xt;
    const int K    = isY ? 768 : 1024;
    const int kit  = K >> 5;       // 24 or 32
    const int rowBase = (blockIdx.x & 127) * 64;

    const int sr = tid >> 3;       // 0..63
    const int sc = tid & 7;        // 0..7 (4-float chunk)

    const float* pA = &A[(size_t)(rowBase + sr) * K + sc * 4];
    const float* pW = &W[(size_t)sr * K + sc * 4];

    f32x4 ra = *reinterpret_cast<const f32x4*>(pA);
    f32x4 rw[4];
    #pragma unroll
    for (int p = 0; p < 4; ++p)
        rw[p] = *reinterpret_cast<const f32x4*>(pW + (size_t)p * 64 * K);

    f32x4 acc[2][4] = {};

    for (int k = 0; k < kit; ++k) {
        __syncthreads();           // prior iter's frag reads done
        {
            bf16x4 h = { (bf16_t)ra.x, (bf16_t)ra.y, (bf16_t)ra.z, (bf16_t)ra.w };
            *reinterpret_cast<bf16x4*>(&Abuf[sr][sc * 4]) = h;
            #pragma unroll
            for (int p = 0; p < 4; ++p) {
                bf16x4 g = { (bf16_t)rw[p].x, (bf16_t)rw[p].y,
                             (bf16_t)rw[p].z, (bf16_t)rw[p].w };
                *reinterpret_cast<bf16x4*>(&Wbuf[p * 64 + sr][sc * 4]) = g;
            }
        }
        if (k + 1 < kit) {         // register prefetch of next 32-K slab
            ra = *reinterpret_cast<const f32x4*>(pA + (k + 1) * 32);
            #pragma unroll
            for (int p = 0; p < 4; ++p)
                rw[p] = *reinterpret_cast<const f32x4*>(pW + (size_t)p * 64 * K + (k + 1) * 32);
        }
        __syncthreads();           // staged tile visible

        bf16x8 aF[2], bF[4];
        #pragma unroll
        for (int mf = 0; mf < 2; ++mf)
            aF[mf] = *reinterpret_cast<const bf16x8*>(&Abuf[wy * 32 + mf * 16 + c16][quad * 8]);
        #pragma unroll
        for (int nf = 0; nf < 4; ++nf)
            bF[nf] = *reinterpret_cast<const bf16x8*>(&Wbuf[wx * 64 + nf * 16 + c16][quad * 8]);
        #pragma unroll
        for (int mf = 0; mf < 2; ++mf)
            #pragma unroll
            for (int nf = 0; nf < 4; ++nf)
                acc[mf][nf] = __builtin_amdgcn_mfma_f32_16x16x32_bf16(
                    aF[mf], bF[nf], acc[mf][nf], 0, 0, 0);
    }

    // ---- epilogue: +bias, row ssq, normalize, fp8 fragment-major store ----
    #pragma unroll
    for (int nf = 0; nf < 4; ++nf) {
        float bb = bias[wx * 64 + nf * 16 + c16];
        #pragma unroll
        for (int mf = 0; mf < 2; ++mf)
            #pragma unroll
            for (int r = 0; r < 4; ++r)
                acc[mf][nf][r] += bb;
    }

    #pragma unroll
    for (int mf = 0; mf < 2; ++mf)
        #pragma unroll
        for (int r = 0; r < 4; ++r) {
            float v = 0.f;
            #pragma unroll
            for (int nf = 0; nf < 4; ++nf)
                v += acc[mf][nf][r] * acc[mf][nf][r];
            v += __shfl_xor(v, 1, 64);
            v += __shfl_xor(v, 2, 64);
            v += __shfl_xor(v, 4, 64);
            v += __shfl_xor(v, 8, 64);
            if (c16 == 0) ssqL[wx][wy * 32 + mf * 16 + quad * 4 + r] = v;
        }
    __syncthreads();   // also: all frag reads done -> obuf region conceptually free

    #pragma unroll
    for (int mf = 0; mf < 2; ++mf)
        #pragma unroll
        for (int r = 0; r < 4; ++r) {
            int lr = wy * 32 + mf * 16 + quad * 4 + r;
            float t = ssqL[0][lr] + ssqL[1][lr] + ssqL[2][lr] + ssqL[3][lr];
            float inv = 1.0f / fmaxf(sqrtf(t), 1e-8f);
            #pragma unroll
            for (int nf = 0; nf < 4; ++nf) {
                int kcol = wx * 64 + nf * 16 + c16;
                obuf[frag_off(lr, kcol)] = cvt1_e4m3(acc[mf][nf][r] * inv);
            }
        }
    __syncthreads();

    // coalesced copy-out: 16KB, 32B/thread
    {
        const f32x4* src = reinterpret_cast<const f32x4*>(&obuf[tid * 32]);
        f32x4* gout = reinterpret_cast<f32x4*>(dst + (size_t)rowBase * 256 + tid * 32);
        gout[0] = src[0];
        gout[1] = src[1];
    }
}

// ---------------------------------------------------------------------------
// sim_gemm: e = exp(Xn @ Yn^T); rowsum/colsum/diag. BM=BN=128, K=256.
// NO LDS in K-loop: inputs are fragment-major, so each wave fragment(-pair)
// is ONE contiguous 1KB global_load_dwordx4 (addr = base + lane*16), L1/L2
// resident (4MB working set). Software-pipelined over 4 K=64 slabs.
// ---------------------------------------------------------------------------
__global__ __launch_bounds__(256) void sim_gemm(
    const unsigned char* __restrict__ Xt, const unsigned char* __restrict__ Yt,
    float* __restrict__ rowsum, float* __restrict__ colsum,
    float* __restrict__ pos)
{
    __shared__ float red[256];

    const int tid  = threadIdx.x;
    const int lane = tid & 63;
    const int wave = tid >> 6;
    const int quad = lane >> 4;
    const int c16  = lane & 15;
    const int wy   = wave >> 1;
    const int wx   = wave & 1;
    const int rowBase = blockIdx.x * 128;
    const int colBase = blockIdx.y * 128;

    // lane address = tileBase + slab*1024 + lane*16  (lane = quad*16+c16? No:
    // lane = c16 + 16*quad reads offset quad*256 + c16*16 = lane-permuted but
    // the WAVE's 64 lanes cover exactly [0,1024) contiguously.)
    const u64x2* pa[4];
    const u64x2* pb[4];
    #pragma unroll
    for (int mf = 0; mf < 4; ++mf)
        pa[mf] = reinterpret_cast<const u64x2*>(
            Xt + (size_t)(rowBase + wy * 64 + mf * 16) * 256 + quad * 256 + c16 * 16);
    #pragma unroll
    for (int nf = 0; nf < 4; ++nf)
        pb[nf] = reinterpret_cast<const u64x2*>(
            Yt + (size_t)(colBase + wx * 64 + nf * 16) * 256 + quad * 256 + c16 * 16);

    f32x4 acc[4][4] = {};

    auto loadf = [&](u64x2* A, u64x2* B, int slab) {
        #pragma unroll
        for (int i = 0; i < 4; ++i) {
            A[i] = pa[i][slab * 64];   // 64 u64x2 = 1024 B slab stride
            B[i] = pb[i][slab * 64];
        }
    };
    auto mm = [&](const u64x2* A, const u64x2* B) {
        #pragma unroll
        for (int mf = 0; mf < 4; ++mf)
            #pragma unroll
            for (int nf = 0; nf < 4; ++nf)
                acc[mf][nf] = __builtin_amdgcn_mfma_f32_16x16x32_fp8_fp8(
                    (long)A[mf].x, (long)B[nf].x, acc[mf][nf], 0, 0, 0);
        #pragma unroll
        for (int mf = 0; mf < 4; ++mf)
            #pragma unroll
            for (int nf = 0; nf < 4; ++nf)
                acc[mf][nf] = __builtin_amdgcn_mfma_f32_16x16x32_fp8_fp8(
                    (long)A[mf].y, (long)B[nf].y, acc[mf][nf], 0, 0, 0);
    };

    u64x2 A0[4], B0[4], A1[4], B1[4];
    loadf(A0, B0, 0);
    loadf(A1, B1, 1);
    mm(A0, B0);
    loadf(A0, B0, 2);
    mm(A1, B1);
    loadf(A1, B1, 3);
    mm(A0, B0);
    mm(A1, B1);

    // ---- epilogue ----
    #pragma unroll
    for (int mf = 0; mf < 4; ++mf)
        #pragma unroll
        for (int nf = 0; nf < 4; ++nf)
            #pragma unroll
            for (int r = 0; r < 4; ++r)
                acc[mf][nf][r] = __expf(acc[mf][nf][r]);   // TAU = 1

    if (rowBase == colBase) {
        #pragma unroll
        for (int mf = 0; mf < 4; ++mf)
            #pragma unroll
            for (int nf = 0; nf < 4; ++nf)
                #pragma unroll
                for (int r = 0; r < 4; ++r) {
                    int lrow = wy * 64 + mf * 16 + quad * 4 + r;
                    int lcol = wx * 64 + nf * 16 + c16;
                    if (lrow == lcol) pos[rowBase + lrow] = acc[mf][nf][r];
                }
    }

    float rs[4][4];
    #pragma unroll
    for (int mf = 0; mf < 4; ++mf)
        #pragma unroll
        for (int r = 0; r < 4; ++r) {
            float v = acc[mf][0][r] + acc[mf][1][r] + acc[mf][2][r] + acc[mf][3][r];
            v += __shfl_xor(v, 1, 64);
            v += __shfl_xor(v, 2, 64);
            v += __shfl_xor(v, 4, 64);
            v += __shfl_xor(v, 8, 64);
            rs[mf][r] = v;
        }

    float cs[4];
    #pragma unroll
    for (int nf = 0; nf < 4; ++nf) {
        float v = 0.f;
        #pragma unroll
        for (int mf = 0; mf < 4; ++mf)
            #pragma unroll
            for (int r = 0; r < 4; ++r)
                v += acc[mf][nf][r];
        v += __shfl_xor(v, 16, 64);
        v += __shfl_xor(v, 32, 64);
        cs[nf] = v;
    }

    red[tid] = 0.f;
    __syncthreads();

    if (c16 == 0) {
        #pragma unroll
        for (int mf = 0; mf < 4; ++mf)
            #pragma unroll
            for (int r = 0; r < 4; ++r)
                atomicAdd(&red[wy * 64 + mf * 16 + quad * 4 + r], rs[mf][r]);
    }
    if (quad == 0) {
        #pragma unroll
        for (int nf = 0; nf < 4; ++nf)
            atomicAdd(&red[128 + wx * 64 + nf * 16 + c16], cs[nf]);
    }
    __syncthreads();

    if (tid < 128) atomicAdd(&rowsum[rowBase + tid], red[tid]);
    else           atomicAdd(&colsum[colBase + tid - 128], red[tid]);
}

// ---------------------------------------------------------------------------
__global__ __launch_bounds__(256) void finalize(
    const float* __restrict__ rowsum, const float* __restrict__ colsum,
    const float* __restrict__ pos, float* __restrict__ out)
{
    int i = blockIdx.x * 256 + threadIdx.x;
    float p = pos[i];
    out[i] = logf(colsum[i] - p) + logf(rowsum[i] - p) - 2.0f * logf(p);
}

// ---------------------------------------------------------------------------
extern "C" void kernel_launch(void* const* d_in, const int* in_sizes, int n_in,
                              void* d_out, int out_size, void* d_ws, size_t ws_size,
                              hipStream_t stream) {
    const float* X  = (const float*)d_in[0];
    const float* Y  = (const float*)d_in[1];
    const float* Wx = (const float*)d_in[2];
    const float* bx = (const float*)d_in[3];
    const float* Wy = (const float*)d_in[4];
    const float* by = (const float*)d_in[5];
    float* out = (float*)d_out;

    char* ws = (char*)d_ws;
    unsigned char* Xt = (unsigned char*)(ws);               // 2 MB fragment-major fp8
    unsigned char* Yt = (unsigned char*)(ws + (2u << 20));  // 2 MB
    float*  rowsum = (float*)(ws + (4u << 20));
    float*  colsum = rowsum + 8192;
    float*  pos    = colsum + 8192;

    proj_norm<<<256, 512, 0, stream>>>(X, Y, Wx, bx, Wy, by, Xt, Yt, rowsum);
    sim_gemm<<<dim3(64, 64), 256, 0, stream>>>(Xt, Yt, rowsum, colsum, pos);
    finalize<<<32, 256, 0, stream>>>(rowsum, colsum, pos, out);
}